// Round 10
// baseline (528.134 us; speedup 1.0000x reference)
//
#include <hip/hip_runtime.h>
#include <hip/hip_bf16.h>
#include <hip/hip_fp16.h>
#include <stdint.h>

#define NNODES 50000
#define NEDGES 800000
#define LOG2E 1.44269504088896340736f

typedef float f32x4 __attribute__((ext_vector_type(4)));
typedef _Float16 half8 __attribute__((ext_vector_type(8)));
typedef _Float16 half2v __attribute__((ext_vector_type(2)));

__device__ __forceinline__ ushort f2h(float f) {
  return __half_as_ushort(__float2half(f));  // RNE
}
__device__ __forceinline__ float2 h2x2(uint32_t u) {
  return __half22float2(__builtin_bit_cast(__half2, u));
}

#if __has_builtin(__builtin_amdgcn_fdot2) && __has_builtin(__builtin_amdgcn_perm) && __has_builtin(__builtin_amdgcn_cvt_pkrtz)
#define USE_DOT2 1
#else
#define USE_DOT2 0
#endif

__device__ __forceinline__ half2v pack2(float a, float b) {
  return __builtin_bit_cast(half2v, __builtin_amdgcn_cvt_pkrtz(a, b));
}

__device__ __forceinline__ float fexp2(float x) {
#if __has_builtin(__builtin_amdgcn_exp2f)
  return __builtin_amdgcn_exp2f(x);
#else
  return exp2f(x);
#endif
}

__device__ __forceinline__ void gload_lds16(const void* g, void* l) {
  __builtin_amdgcn_global_load_lds(
      (const __attribute__((address_space(1))) uint32_t*)g,
      (__attribute__((address_space(3))) uint32_t*)l, 16, 0, 0);
}

// ---------------------------------------------------------------------------
// fp16 MFMA GEMM, layers 1/2: C[M,256] = A @ Wt^T, fused alpha epilogue.
// BM=64, BN=256 (A panel read once), BK=64. fp16 out.
// alpha written HEAD-MAJOR: as_out[head*M + node] (so the sliced aggregation
// keeps a 200KB-per-head hot set in each XCD's L2). LOG2E pre-scaled.
// ---------------------------------------------------------------------------
__global__ __launch_bounds__(256) void gemm_wide(
    const ushort* __restrict__ A, const ushort* __restrict__ B,
    const float* __restrict__ a_src, const float* __restrict__ a_dst,
    float* __restrict__ as_out, float* __restrict__ ad_out,
    ushort* __restrict__ Cout, int M, int K) {
  __shared__ ushort As[64 * 64];    // 8 KB
  __shared__ ushort Bs[256 * 64];   // 32 KB

  const int t = threadIdx.x;
  const int w = t >> 6, ln = t & 63;
  const int row0 = blockIdx.x * 64;
  const int wr = (w >> 1) * 32, wc = (w & 1) * 128;

  f32x4 acc[2][8] = {};

  const int nkt = K >> 6;
  for (int kt = 0; kt < nkt; ++kt) {
    const int k0 = kt << 6;
    #pragma unroll
    for (int i = 0; i < 2; ++i) {
      int row8 = w * 2 + i;
      int rloc = row8 * 8 + (ln >> 3);
      int slot = (ln & 7) ^ (rloc & 7);
      int grow = row0 + rloc; grow = grow < M ? grow : M - 1;
      gload_lds16(A + (size_t)grow * K + k0 + slot * 8, As + row8 * 512);
    }
    #pragma unroll
    for (int i = 0; i < 8; ++i) {
      int row8 = w * 8 + i;
      int rloc = row8 * 8 + (ln >> 3);
      int slot = (ln & 7) ^ (rloc & 7);
      gload_lds16(B + (size_t)rloc * K + k0 + slot * 8, Bs + row8 * 512);
    }
    __syncthreads();

    #pragma unroll
    for (int ks = 0; ks < 2; ++ks) {
      half8 a[2], b[8];
      #pragma unroll
      for (int i = 0; i < 2; ++i) {
        int row = wr + i * 16 + (ln & 15);
        int slot = (ks * 4 + (ln >> 4)) ^ (row & 7);
        a[i] = *(const half8*)(As + row * 64 + slot * 8);
      }
      #pragma unroll
      for (int j = 0; j < 8; ++j) {
        int col = wc + j * 16 + (ln & 15);
        int slot = (ks * 4 + (ln >> 4)) ^ (col & 7);
        b[j] = *(const half8*)(Bs + col * 64 + slot * 8);
      }
      #pragma unroll
      for (int i = 0; i < 2; ++i)
        #pragma unroll
        for (int j = 0; j < 8; ++j)
          acc[i][j] = __builtin_amdgcn_mfma_f32_16x16x32_f16(a[i], b[j], acc[i][j], 0, 0, 0);
    }
    __syncthreads();
  }

  const int lx = ln & 15, g = ln >> 4;

  #pragma unroll
  for (int i = 0; i < 2; ++i)
    #pragma unroll
    for (int j = 0; j < 8; ++j)
      #pragma unroll
      for (int r = 0; r < 4; ++r) {
        int grow = row0 + wr + i * 16 + g * 4 + r;
        int gcol = wc + j * 16 + lx;
        if (grow < M) Cout[(size_t)grow * 256 + gcol] = f2h(acc[i][j][r]);
      }

  // ---- fused alpha epilogue (LOG2E pre-scaled, head-major out) ----
  const int hbase = wc >> 5;
  float avs[8], avd[8];
  #pragma unroll
  for (int j = 0; j < 8; ++j) {
    avs[j] = a_src[wc + j * 16 + lx] * LOG2E;
    avd[j] = a_dst[wc + j * 16 + lx] * LOG2E;
  }
  #pragma unroll
  for (int i = 0; i < 2; ++i)
    #pragma unroll
    for (int r = 0; r < 4; ++r) {
      float ps[4] = {0.f, 0.f, 0.f, 0.f}, pd[4] = {0.f, 0.f, 0.f, 0.f};
      #pragma unroll
      for (int j = 0; j < 8; ++j) {
        float v = acc[i][j][r];
        ps[j >> 1] += v * avs[j];
        pd[j >> 1] += v * avd[j];
      }
      #pragma unroll
      for (int m = 1; m < 16; m <<= 1)
        #pragma unroll
        for (int q = 0; q < 4; ++q) {
          ps[q] += __shfl_xor(ps[q], m);
          pd[q] += __shfl_xor(pd[q], m);
        }
      if (lx == 0) {
        int grow = row0 + wr + i * 16 + g * 4 + r;
        if (grow < M) {
          #pragma unroll
          for (int q = 0; q < 4; ++q) {
            as_out[(size_t)(hbase + q) * M + grow] = ps[q];
            ad_out[(size_t)(hbase + q) * M + grow] = pd[q];
          }
        }
      }
    }
}

// ---------------------------------------------------------------------------
// fp16 MFMA GEMM, layer 3 (Ncols=64): BM=128, BN=64, BK=64. fp16 out.
// Fused alpha (H=1, C=64), LOG2E pre-scaled.
// ---------------------------------------------------------------------------
__global__ __launch_bounds__(256) void gemm_mfma3(
    const ushort* __restrict__ A, const ushort* __restrict__ B,
    const float* __restrict__ a_src, const float* __restrict__ a_dst,
    float* __restrict__ as_out, float* __restrict__ ad_out,
    ushort* __restrict__ Cout, int M, int K, int Ncols) {
  __shared__ ushort As[128 * 64];
  __shared__ ushort Bs[64 * 64];
  __shared__ float redS[2][128], redD[2][128];

  const int t = threadIdx.x;
  const int w = t >> 6, ln = t & 63;
  const int row0 = blockIdx.y * 128;
  const int col0 = blockIdx.x * 64;
  const int wr = (w >> 1) * 64, wc = (w & 1) * 32;

  f32x4 acc[4][2] = {};

  const int nkt = K >> 6;
  for (int kt = 0; kt < nkt; ++kt) {
    const int k0 = kt << 6;
    #pragma unroll
    for (int i = 0; i < 4; ++i) {
      int row8 = w * 4 + i;
      int rloc = row8 * 8 + (ln >> 3);
      int slot = (ln & 7) ^ (rloc & 7);
      int grow = row0 + rloc; grow = grow < M ? grow : M - 1;
      gload_lds16(A + (size_t)grow * K + k0 + slot * 8, As + row8 * 512);
    }
    #pragma unroll
    for (int i = 0; i < 2; ++i) {
      int row8 = w * 2 + i;
      int rloc = row8 * 8 + (ln >> 3);
      int slot = (ln & 7) ^ (rloc & 7);
      gload_lds16(B + (size_t)(col0 + rloc) * K + k0 + slot * 8, Bs + row8 * 512);
    }
    __syncthreads();

    #pragma unroll
    for (int ks = 0; ks < 2; ++ks) {
      half8 a[4], b[2];
      #pragma unroll
      for (int i = 0; i < 4; ++i) {
        int row = wr + i * 16 + (ln & 15);
        int slot = (ks * 4 + (ln >> 4)) ^ (row & 7);
        a[i] = *(const half8*)(As + row * 64 + slot * 8);
      }
      #pragma unroll
      for (int j = 0; j < 2; ++j) {
        int col = wc + j * 16 + (ln & 15);
        int slot = (ks * 4 + (ln >> 4)) ^ (col & 7);
        b[j] = *(const half8*)(Bs + col * 64 + slot * 8);
      }
      #pragma unroll
      for (int i = 0; i < 4; ++i)
        #pragma unroll
        for (int j = 0; j < 2; ++j)
          acc[i][j] = __builtin_amdgcn_mfma_f32_16x16x32_f16(a[i], b[j], acc[i][j], 0, 0, 0);
    }
    __syncthreads();
  }

  const int lx = ln & 15, g = ln >> 4;

  #pragma unroll
  for (int i = 0; i < 4; ++i)
    #pragma unroll
    for (int j = 0; j < 2; ++j)
      #pragma unroll
      for (int r = 0; r < 4; ++r) {
        int grow = row0 + wr + i * 16 + g * 4 + r;
        int gcol = col0 + wc + j * 16 + lx;
        if (grow < M) Cout[(size_t)grow * Ncols + gcol] = f2h(acc[i][j][r]);
      }

  float avs[2], avd[2];
  #pragma unroll
  for (int j = 0; j < 2; ++j) {
    avs[j] = a_src[wc + j * 16 + lx] * LOG2E;
    avd[j] = a_dst[wc + j * 16 + lx] * LOG2E;
  }
  #pragma unroll
  for (int i = 0; i < 4; ++i)
    #pragma unroll
    for (int r = 0; r < 4; ++r) {
      float ps = 0.f, pd = 0.f;
      #pragma unroll
      for (int j = 0; j < 2; ++j) {
        float v = acc[i][j][r];
        ps += v * avs[j];
        pd += v * avd[j];
      }
      #pragma unroll
      for (int m = 1; m < 16; m <<= 1) {
        ps += __shfl_xor(ps, m);
        pd += __shfl_xor(pd, m);
      }
      if (lx == 0) {
        int lrow = wr + i * 16 + g * 4 + r;
        redS[w & 1][lrow] = ps;
        redD[w & 1][lrow] = pd;
      }
    }
  __syncthreads();
  if (t < 128) {
    int grow = row0 + t;
    if (grow < M) {
      as_out[grow] = redS[0][t] + redS[1][t];
      ad_out[grow] = redD[0][t] + redD[1][t];
    }
  }
}

// ---------------------------------------------------------------------------
__global__ void cvt_h(const float* __restrict__ in, ushort* __restrict__ out, int n4) {
  int idx = blockIdx.x * blockDim.x + threadIdx.x;
  if (idx >= n4) return;
  float4 v = ((const float4*)in)[idx];
  ushort4 o;
  o.x = f2h(v.x); o.y = f2h(v.y); o.z = f2h(v.z); o.w = f2h(v.w);
  ((ushort4*)out)[idx] = o;
}

// All three weight transposes fused (tiny): W[K][N] f32 -> Wt[N][K] fp16.
__global__ void cvt_w_all(const float* __restrict__ W1, const float* __restrict__ W2,
                          const float* __restrict__ W3, ushort* __restrict__ w1t,
                          ushort* __restrict__ w2t, ushort* __restrict__ w3t) {
  int idx = blockIdx.x * blockDim.x + threadIdx.x;
  if (idx < 32768) {                       // W1: 128x256
    int k = idx >> 8, c = idx & 255;
    w1t[(size_t)c * 128 + k] = f2h(W1[idx]);
  } else if (idx < 32768 + 65536) {        // W2: 256x256
    int j = idx - 32768;
    int k = j >> 8, c = j & 255;
    w2t[(size_t)c * 256 + k] = f2h(W2[j]);
  } else if (idx < 32768 + 65536 + 16384) {  // W3: 256x64
    int j = idx - 98304;
    int k = j >> 6, c = j & 63;
    w3t[(size_t)c * 256 + k] = f2h(W3[j]);
  }
}

// ---------------------------------------------------------------------------
// CSR build
// ---------------------------------------------------------------------------
__global__ void deg_kernel(const int* __restrict__ dst, int* __restrict__ deg, int E) {
  int e = blockIdx.x * blockDim.x + threadIdx.x;
  if (e < E) atomicAdd(&deg[dst[e]], 1);
}

__global__ __launch_bounds__(256) void scan_partial(const int* __restrict__ deg,
                                                    int* __restrict__ rowptr,
                                                    int* __restrict__ blocksum, int n) {
  __shared__ int sdata[256];
  int t = threadIdx.x;
  int base = blockIdx.x * 1024 + t * 4;
  int v[4], s = 0;
  #pragma unroll
  for (int i = 0; i < 4; ++i) {
    v[i] = (base + i < n) ? deg[base + i] : 0;
    s += v[i];
  }
  sdata[t] = s;
  __syncthreads();
  for (int off = 1; off < 256; off <<= 1) {
    int x = (t >= off) ? sdata[t - off] : 0;
    __syncthreads();
    sdata[t] += x;
    __syncthreads();
  }
  int run = sdata[t] - s;
  #pragma unroll
  for (int i = 0; i < 4; ++i) {
    if (base + i < n) rowptr[base + i] = run;
    run += v[i];
  }
  if (t == 255) blocksum[blockIdx.x] = sdata[255];
}

__global__ __launch_bounds__(256) void scan_blocksums(int* __restrict__ blocksum, int nb) {
  __shared__ int sdata[256];
  int t = threadIdx.x;
  int v = (t < nb) ? blocksum[t] : 0;
  sdata[t] = v;
  __syncthreads();
  for (int off = 1; off < 256; off <<= 1) {
    int x = (t >= off) ? sdata[t - off] : 0;
    __syncthreads();
    sdata[t] += x;
    __syncthreads();
  }
  if (t < nb) blocksum[t] = sdata[t] - v;
}

__global__ void scan_add(int* __restrict__ rowptr, const int* __restrict__ blocksum,
                         int* __restrict__ cursor, int n, int E) {
  int idx = blockIdx.x * blockDim.x + threadIdx.x;
  if (idx < n) {
    rowptr[idx] += blocksum[idx >> 10];
    cursor[idx] = 0;
  }
  if (idx == n) rowptr[n] = E;
}

__global__ void scatter_kernel(const int* __restrict__ src, const int* __restrict__ dst,
                               const int* __restrict__ rowptr, int* __restrict__ cursor,
                               int* __restrict__ col_src, int E) {
  int e = blockIdx.x * blockDim.x + threadIdx.x;
  if (e >= E) return;
  int d = dst[e];
  int pos = rowptr[d] + atomicAdd(&cursor[d], 1);
  col_src[pos] = src[e];
}

// ---------------------------------------------------------------------------
// XCD-sliced per-dst softmax + aggregate (layers 1/2).
// slice = blockIdx & 7 (one head = 32 ch = 64B of each h row). With
// round-robin block->XCD dispatch, XCD k only ever touches h columns of
// slice k (3.2 MB) + head-k alpha (200 KB) -> L2-resident gathers.
// 1 dst/wave: 8 edge-groups x 8 lanes x 4ch; cross-group shfl reduce.
// as_/ad_ are head-major [head][node], LOG2E-scaled.
// ---------------------------------------------------------------------------
__global__ __launch_bounds__(256) void aggr_slice(
    const int* __restrict__ rowptr, const int* __restrict__ col_src,
    const ushort* __restrict__ h, const float* __restrict__ as_,
    const float* __restrict__ ad_, const float* __restrict__ bias,
    ushort* __restrict__ of, int n) {
  int bid = blockIdx.x;
  int slice = bid & 7;
  int d = (bid >> 3) * 4 + (threadIdx.x >> 6);
  if (d >= n) return;
  int lane = threadIdx.x & 63;
  int g = lane >> 3;   // edge group 0..7
  int l = lane & 7;    // channel lane: 4 ch each
  const float* asl = as_ + (size_t)slice * n;
  float ad_d = ad_[(size_t)slice * n + d];
  const ushort* hp = h + slice * 32 + l * 4;
  float a0 = 0.f, a1 = 0.f, a2 = 0.f, a3 = 0.f, denom = 0.f;
  int beg = rowptr[d], end = rowptr[d + 1];
  for (int i = beg + g; i < end; i += 8) {
    int s = col_src[i];
    float lg = asl[s] + ad_d;
    float ev = fexp2(fmaxf(lg, 0.2f * lg));
    denom += ev;
    uint2 v = *(const uint2*)(hp + (size_t)s * 256);
    float2 p0 = h2x2(v.x), p1 = h2x2(v.y);
    a0 += ev * p0.x;
    a1 += ev * p0.y;
    a2 += ev * p1.x;
    a3 += ev * p1.y;
  }
  #pragma unroll
  for (int m = 8; m < 64; m <<= 1) {
    a0 += __shfl_xor(a0, m);
    a1 += __shfl_xor(a1, m);
    a2 += __shfl_xor(a2, m);
    a3 += __shfl_xor(a3, m);
    denom += __shfl_xor(denom, m);
  }
  if (g == 0) {
    float inv = 1.f / (denom + 1e-16f);
    int c0 = slice * 32 + l * 4;
    float v0 = a0 * inv + bias[c0 + 0];
    float v1 = a1 * inv + bias[c0 + 1];
    float v2 = a2 * inv + bias[c0 + 2];
    float v3 = a3 * inv + bias[c0 + 3];
    v0 = (v0 > 0.f) ? v0 : expm1f(v0);
    v1 = (v1 > 0.f) ? v1 : expm1f(v1);
    v2 = (v2 > 0.f) ? v2 : expm1f(v2);
    v3 = (v3 > 0.f) ? v3 : expm1f(v3);
    ushort4 hh;
    hh.x = f2h(v0); hh.y = f2h(v1); hh.z = f2h(v2); hh.w = f2h(v3);
    *(ushort4*)(of + (size_t)d * 256 + c0) = hh;
  }
}

// Layer 3: fp16 h gather (6.4MB, near-L2), 4 dst/wave, fdot2 MAC, fp32 out.
__global__ __launch_bounds__(256) void aggr_f3(
    const int* __restrict__ rowptr, const int* __restrict__ col_src,
    const ushort* __restrict__ h, const float* __restrict__ as_,
    const float* __restrict__ ad_, const float* __restrict__ bias,
    float* __restrict__ outp, int n) {
  int wid = (blockIdx.x * 256 + threadIdx.x) >> 6;
  int d = wid * 4 + ((threadIdx.x >> 4) & 3);
  if (d >= n) return;
  int l = threadIdx.x & 15;
  int c0 = l * 4;
  float ad_d = ad_[d];
  float a0 = 0.f, a1 = 0.f, a2 = 0.f, a3 = 0.f, denom = 0.f;
  const ushort* hp = h + c0;
  int beg = rowptr[d], end = rowptr[d + 1];
  int i = beg;
#if USE_DOT2
  const half2v onepk = {(_Float16)1.f, (_Float16)1.f};
  for (; i + 2 <= end; i += 2) {
    int s0 = col_src[i], s1 = col_src[i + 1];
    float l0 = as_[s0] + ad_d;
    float l1 = as_[s1] + ad_d;
    uint2 v0 = *(const uint2*)(hp + (size_t)s0 * 64);
    uint2 v1 = *(const uint2*)(hp + (size_t)s1 * 64);
    float e0 = fexp2(fmaxf(l0, 0.2f * l0));
    float e1 = fexp2(fmaxf(l1, 0.2f * l1));
    half2v ep = pack2(e0, e1);
    denom = __builtin_amdgcn_fdot2(ep, onepk, denom, false);
    uint32_t p;
    p = __builtin_amdgcn_perm(v1.x, v0.x, 0x05040100u);
    a0 = __builtin_amdgcn_fdot2(ep, __builtin_bit_cast(half2v, p), a0, false);
    p = __builtin_amdgcn_perm(v1.x, v0.x, 0x07060302u);
    a1 = __builtin_amdgcn_fdot2(ep, __builtin_bit_cast(half2v, p), a1, false);
    p = __builtin_amdgcn_perm(v1.y, v0.y, 0x05040100u);
    a2 = __builtin_amdgcn_fdot2(ep, __builtin_bit_cast(half2v, p), a2, false);
    p = __builtin_amdgcn_perm(v1.y, v0.y, 0x07060302u);
    a3 = __builtin_amdgcn_fdot2(ep, __builtin_bit_cast(half2v, p), a3, false);
  }
#endif
  for (; i < end; ++i) {
    int s = col_src[i];
    float lg = as_[s] + ad_d;
    float ev = fexp2(fmaxf(lg, 0.2f * lg));
    denom += ev;
    uint2 v = *(const uint2*)(hp + (size_t)s * 64);
    float2 p0 = h2x2(v.x), p1 = h2x2(v.y);
    a0 += ev * p0.x;
    a1 += ev * p0.y;
    a2 += ev * p1.x;
    a3 += ev * p1.y;
  }
  float inv = 1.f / (denom + 1e-16f);
  float4 r;
  r.x = a0 * inv + bias[c0 + 0];
  r.y = a1 * inv + bias[c0 + 1];
  r.z = a2 * inv + bias[c0 + 2];
  r.w = a3 * inv + bias[c0 + 3];
  *(float4*)(outp + (size_t)d * 64 + c0) = r;
}

// ---------------------------------------------------------------------------

extern "C" void kernel_launch(void* const* d_in, const int* in_sizes, int n_in,
                              void* d_out, int out_size, void* d_ws, size_t ws_size,
                              hipStream_t stream) {
  const float* x   = (const float*)d_in[0];
  const int*   ei  = (const int*)d_in[1];
  const float* W1  = (const float*)d_in[2];
  const float* aS1 = (const float*)d_in[3];
  const float* aD1 = (const float*)d_in[4];
  const float* b1  = (const float*)d_in[5];
  const float* W2  = (const float*)d_in[6];
  const float* aS2 = (const float*)d_in[7];
  const float* aD2 = (const float*)d_in[8];
  const float* b2  = (const float*)d_in[9];
  const float* W3  = (const float*)d_in[10];
  const float* aS3 = (const float*)d_in[11];
  const float* aD3 = (const float*)d_in[12];
  const float* b3  = (const float*)d_in[13];

  const int* srcp = ei;
  const int* dstp = ei + NEDGES;

  // ---- arena (~72 MB) ----
  char* base = (char*)d_ws;
  size_t o = 0;
  ushort* hbf  = (ushort*)(base + o); o += 25600000;
  ushort* ff   = (ushort*)(base + o); o += 25600000;
  ushort* f1   = (ushort*)(base + o); o += 12800000;
  float*  as_  = (float*)(base + o);  o += 1600000;
  float*  ad_  = (float*)(base + o);  o += 1600000;
  ushort* w1t  = (ushort*)(base + o); o += 65536;
  ushort* w2t  = (ushort*)(base + o); o += 131072;
  ushort* w3t  = (ushort*)(base + o); o += 32768;
  int* rowptr  = (int*)(base + o);    o += 200016;
  int* cursor  = (int*)(base + o);    o += 200000;
  int* colsrc  = (int*)(base + o);    o += 3200000;
  int* bsum    = (int*)(base + o);    o += 1024;
  float* outp  = (float*)d_out;

  // ---- CSR build ----
  hipMemsetAsync(cursor, 0, NNODES * sizeof(int), stream);
  deg_kernel<<<(NEDGES + 255) / 256, 256, 0, stream>>>(dstp, cursor, NEDGES);
  int nb = (NNODES + 1023) / 1024;  // 49
  scan_partial<<<nb, 256, 0, stream>>>(cursor, rowptr, bsum, NNODES);
  scan_blocksums<<<1, 256, 0, stream>>>(bsum, nb);
  scan_add<<<(NNODES + 256) / 256, 256, 0, stream>>>(rowptr, bsum, cursor, NNODES, NEDGES);
  scatter_kernel<<<(NEDGES + 255) / 256, 256, 0, stream>>>(srcp, dstp, rowptr, cursor,
                                                           colsrc, NEDGES);

  // ---- conversions ----
  cvt_h<<<(NNODES * 128 / 4 + 255) / 256, 256, 0, stream>>>(x, f1, NNODES * 128 / 4);
  cvt_w_all<<<(114688 + 255) / 256, 256, 0, stream>>>(W1, W2, W3, w1t, w2t, w3t);

  const int gs  = 8 * ((NNODES + 3) / 4);  // aggr_slice: 8 slices x N/4 blocks
  const int ga4 = (NNODES + 15) / 16;      // aggr_f3
  const int gw  = (NNODES + 63) / 64;      // gemm_wide grid
  // ---- layer 1 ----
  gemm_wide<<<gw, 256, 0, stream>>>(f1, w1t, aS1, aD1, as_, ad_, hbf, NNODES, 128);
  aggr_slice<<<gs, 256, 0, stream>>>(rowptr, colsrc, hbf, as_, ad_, b1, ff, NNODES);
  // ---- layer 2 ----
  gemm_wide<<<gw, 256, 0, stream>>>(ff, w2t, aS2, aD2, as_, ad_, hbf, NNODES, 256);
  aggr_slice<<<gs, 256, 0, stream>>>(rowptr, colsrc, hbf, as_, ad_, b2, ff, NNODES);
  // ---- layer 3 ----
  gemm_mfma3<<<dim3(1, (NNODES + 127) / 128), 256, 0, stream>>>(
      ff, w3t, aS3, aD3, as_, ad_, hbf, NNODES, 256, 64);
  aggr_f3<<<ga4, 256, 0, stream>>>(rowptr, colsrc, hbf, as_, ad_, b3, outp, NNODES);
}

// Round 11
// 324.124 us; speedup vs baseline: 1.6294x; 1.6294x over previous
//
#include <hip/hip_runtime.h>
#include <hip/hip_bf16.h>
#include <hip/hip_fp16.h>
#include <stdint.h>

#define NNODES 50000
#define NEDGES 800000
#define LOG2E 1.44269504088896340736f

typedef float f32x4 __attribute__((ext_vector_type(4)));
typedef _Float16 half8 __attribute__((ext_vector_type(8)));
typedef _Float16 half2v __attribute__((ext_vector_type(2)));
typedef unsigned short ushort8v __attribute__((ext_vector_type(8)));

__device__ __forceinline__ ushort f2h(float f) {
  return __half_as_ushort(__float2half(f));  // RNE
}
__device__ __forceinline__ float2 h2x2(uint32_t u) {
  return __half22float2(__builtin_bit_cast(__half2, u));
}

#if __has_builtin(__builtin_amdgcn_fdot2) && __has_builtin(__builtin_amdgcn_perm) && __has_builtin(__builtin_amdgcn_cvt_pkrtz)
#define USE_DOT2 1
#else
#define USE_DOT2 0
#endif

__device__ __forceinline__ half2v pack2(float a, float b) {
  return __builtin_bit_cast(half2v, __builtin_amdgcn_cvt_pkrtz(a, b));
}

__device__ __forceinline__ float fexp2(float x) {
#if __has_builtin(__builtin_amdgcn_exp2f)
  return __builtin_amdgcn_exp2f(x);
#else
  return exp2f(x);
#endif
}

__device__ __forceinline__ void gload_lds16(const void* g, void* l) {
  __builtin_amdgcn_global_load_lds(
      (const __attribute__((address_space(1))) uint32_t*)g,
      (__attribute__((address_space(3))) uint32_t*)l, 16, 0, 0);
}

// ---------------------------------------------------------------------------
// fp16 MFMA GEMM, layers 1/2: C[M,256] = A @ Wt^T, fused alpha epilogue.
// BM=64, BN=256 (A panel read once), BK=64. fp16 out. Node-major alpha,
// LOG2E pre-scaled.
// ---------------------------------------------------------------------------
__global__ __launch_bounds__(256) void gemm_wide(
    const ushort* __restrict__ A, const ushort* __restrict__ B,
    const float* __restrict__ a_src, const float* __restrict__ a_dst,
    float* __restrict__ as_out, float* __restrict__ ad_out,
    ushort* __restrict__ Cout, int M, int K) {
  __shared__ ushort As[64 * 64];    // 8 KB
  __shared__ ushort Bs[256 * 64];   // 32 KB

  const int t = threadIdx.x;
  const int w = t >> 6, ln = t & 63;
  const int row0 = blockIdx.x * 64;
  const int wr = (w >> 1) * 32, wc = (w & 1) * 128;

  f32x4 acc[2][8] = {};

  const int nkt = K >> 6;
  for (int kt = 0; kt < nkt; ++kt) {
    const int k0 = kt << 6;
    #pragma unroll
    for (int i = 0; i < 2; ++i) {
      int row8 = w * 2 + i;
      int rloc = row8 * 8 + (ln >> 3);
      int slot = (ln & 7) ^ (rloc & 7);
      int grow = row0 + rloc; grow = grow < M ? grow : M - 1;
      gload_lds16(A + (size_t)grow * K + k0 + slot * 8, As + row8 * 512);
    }
    #pragma unroll
    for (int i = 0; i < 8; ++i) {
      int row8 = w * 8 + i;
      int rloc = row8 * 8 + (ln >> 3);
      int slot = (ln & 7) ^ (rloc & 7);
      gload_lds16(B + (size_t)rloc * K + k0 + slot * 8, Bs + row8 * 512);
    }
    __syncthreads();

    #pragma unroll
    for (int ks = 0; ks < 2; ++ks) {
      half8 a[2], b[8];
      #pragma unroll
      for (int i = 0; i < 2; ++i) {
        int row = wr + i * 16 + (ln & 15);
        int slot = (ks * 4 + (ln >> 4)) ^ (row & 7);
        a[i] = *(const half8*)(As + row * 64 + slot * 8);
      }
      #pragma unroll
      for (int j = 0; j < 8; ++j) {
        int col = wc + j * 16 + (ln & 15);
        int slot = (ks * 4 + (ln >> 4)) ^ (col & 7);
        b[j] = *(const half8*)(Bs + col * 64 + slot * 8);
      }
      #pragma unroll
      for (int i = 0; i < 2; ++i)
        #pragma unroll
        for (int j = 0; j < 8; ++j)
          acc[i][j] = __builtin_amdgcn_mfma_f32_16x16x32_f16(a[i], b[j], acc[i][j], 0, 0, 0);
    }
    __syncthreads();
  }

  const int lx = ln & 15, g = ln >> 4;

  #pragma unroll
  for (int i = 0; i < 2; ++i)
    #pragma unroll
    for (int j = 0; j < 8; ++j)
      #pragma unroll
      for (int r = 0; r < 4; ++r) {
        int grow = row0 + wr + i * 16 + g * 4 + r;
        int gcol = wc + j * 16 + lx;
        if (grow < M) Cout[(size_t)grow * 256 + gcol] = f2h(acc[i][j][r]);
      }

  // ---- fused alpha epilogue (LOG2E pre-scaled, node-major) ----
  const int hbase = wc >> 5;
  float avs[8], avd[8];
  #pragma unroll
  for (int j = 0; j < 8; ++j) {
    avs[j] = a_src[wc + j * 16 + lx] * LOG2E;
    avd[j] = a_dst[wc + j * 16 + lx] * LOG2E;
  }
  #pragma unroll
  for (int i = 0; i < 2; ++i)
    #pragma unroll
    for (int r = 0; r < 4; ++r) {
      float ps[4] = {0.f, 0.f, 0.f, 0.f}, pd[4] = {0.f, 0.f, 0.f, 0.f};
      #pragma unroll
      for (int j = 0; j < 8; ++j) {
        float v = acc[i][j][r];
        ps[j >> 1] += v * avs[j];
        pd[j >> 1] += v * avd[j];
      }
      #pragma unroll
      for (int m = 1; m < 16; m <<= 1)
        #pragma unroll
        for (int q = 0; q < 4; ++q) {
          ps[q] += __shfl_xor(ps[q], m);
          pd[q] += __shfl_xor(pd[q], m);
        }
      if (lx == 0) {
        int grow = row0 + wr + i * 16 + g * 4 + r;
        if (grow < M) {
          #pragma unroll
          for (int q = 0; q < 4; ++q) {
            as_out[grow * 8 + hbase + q] = ps[q];
            ad_out[grow * 8 + hbase + q] = pd[q];
          }
        }
      }
    }
}

// ---------------------------------------------------------------------------
// fp16 MFMA GEMM, layer 3 (Ncols=64): BM=128, BN=64, BK=64. fp16 out.
// Fused alpha (H=1, C=64), LOG2E pre-scaled.
// ---------------------------------------------------------------------------
__global__ __launch_bounds__(256) void gemm_mfma3(
    const ushort* __restrict__ A, const ushort* __restrict__ B,
    const float* __restrict__ a_src, const float* __restrict__ a_dst,
    float* __restrict__ as_out, float* __restrict__ ad_out,
    ushort* __restrict__ Cout, int M, int K, int Ncols) {
  __shared__ ushort As[128 * 64];
  __shared__ ushort Bs[64 * 64];
  __shared__ float redS[2][128], redD[2][128];

  const int t = threadIdx.x;
  const int w = t >> 6, ln = t & 63;
  const int row0 = blockIdx.y * 128;
  const int col0 = blockIdx.x * 64;
  const int wr = (w >> 1) * 64, wc = (w & 1) * 32;

  f32x4 acc[4][2] = {};

  const int nkt = K >> 6;
  for (int kt = 0; kt < nkt; ++kt) {
    const int k0 = kt << 6;
    #pragma unroll
    for (int i = 0; i < 4; ++i) {
      int row8 = w * 4 + i;
      int rloc = row8 * 8 + (ln >> 3);
      int slot = (ln & 7) ^ (rloc & 7);
      int grow = row0 + rloc; grow = grow < M ? grow : M - 1;
      gload_lds16(A + (size_t)grow * K + k0 + slot * 8, As + row8 * 512);
    }
    #pragma unroll
    for (int i = 0; i < 2; ++i) {
      int row8 = w * 2 + i;
      int rloc = row8 * 8 + (ln >> 3);
      int slot = (ln & 7) ^ (rloc & 7);
      gload_lds16(B + (size_t)(col0 + rloc) * K + k0 + slot * 8, Bs + row8 * 512);
    }
    __syncthreads();

    #pragma unroll
    for (int ks = 0; ks < 2; ++ks) {
      half8 a[4], b[2];
      #pragma unroll
      for (int i = 0; i < 4; ++i) {
        int row = wr + i * 16 + (ln & 15);
        int slot = (ks * 4 + (ln >> 4)) ^ (row & 7);
        a[i] = *(const half8*)(As + row * 64 + slot * 8);
      }
      #pragma unroll
      for (int j = 0; j < 2; ++j) {
        int col = wc + j * 16 + (ln & 15);
        int slot = (ks * 4 + (ln >> 4)) ^ (col & 7);
        b[j] = *(const half8*)(Bs + col * 64 + slot * 8);
      }
      #pragma unroll
      for (int i = 0; i < 4; ++i)
        #pragma unroll
        for (int j = 0; j < 2; ++j)
          acc[i][j] = __builtin_amdgcn_mfma_f32_16x16x32_f16(a[i], b[j], acc[i][j], 0, 0, 0);
    }
    __syncthreads();
  }

  const int lx = ln & 15, g = ln >> 4;

  #pragma unroll
  for (int i = 0; i < 4; ++i)
    #pragma unroll
    for (int j = 0; j < 2; ++j)
      #pragma unroll
      for (int r = 0; r < 4; ++r) {
        int grow = row0 + wr + i * 16 + g * 4 + r;
        int gcol = col0 + wc + j * 16 + lx;
        if (grow < M) Cout[(size_t)grow * Ncols + gcol] = f2h(acc[i][j][r]);
      }

  float avs[2], avd[2];
  #pragma unroll
  for (int j = 0; j < 2; ++j) {
    avs[j] = a_src[wc + j * 16 + lx] * LOG2E;
    avd[j] = a_dst[wc + j * 16 + lx] * LOG2E;
  }
  #pragma unroll
  for (int i = 0; i < 4; ++i)
    #pragma unroll
    for (int r = 0; r < 4; ++r) {
      float ps = 0.f, pd = 0.f;
      #pragma unroll
      for (int j = 0; j < 2; ++j) {
        float v = acc[i][j][r];
        ps += v * avs[j];
        pd += v * avd[j];
      }
      #pragma unroll
      for (int m = 1; m < 16; m <<= 1) {
        ps += __shfl_xor(ps, m);
        pd += __shfl_xor(pd, m);
      }
      if (lx == 0) {
        int lrow = wr + i * 16 + g * 4 + r;
        redS[w & 1][lrow] = ps;
        redD[w & 1][lrow] = pd;
      }
    }
  __syncthreads();
  if (t < 128) {
    int grow = row0 + t;
    if (grow < M) {
      as_out[grow] = redS[0][t] + redS[1][t];
      ad_out[grow] = redD[0][t] + redD[1][t];
    }
  }
}

// ---------------------------------------------------------------------------
__global__ void cvt_h(const float* __restrict__ in, ushort* __restrict__ out, int n4) {
  int idx = blockIdx.x * blockDim.x + threadIdx.x;
  if (idx >= n4) return;
  float4 v = ((const float4*)in)[idx];
  ushort4 o;
  o.x = f2h(v.x); o.y = f2h(v.y); o.z = f2h(v.z); o.w = f2h(v.w);
  ((ushort4*)out)[idx] = o;
}

// All three weight transposes fused (tiny): W[K][N] f32 -> Wt[N][K] fp16.
__global__ void cvt_w_all(const float* __restrict__ W1, const float* __restrict__ W2,
                          const float* __restrict__ W3, ushort* __restrict__ w1t,
                          ushort* __restrict__ w2t, ushort* __restrict__ w3t) {
  int idx = blockIdx.x * blockDim.x + threadIdx.x;
  if (idx < 32768) {                       // W1: 128x256
    int k = idx >> 8, c = idx & 255;
    w1t[(size_t)c * 128 + k] = f2h(W1[idx]);
  } else if (idx < 32768 + 65536) {        // W2: 256x256
    int j = idx - 32768;
    int k = j >> 8, c = j & 255;
    w2t[(size_t)c * 256 + k] = f2h(W2[j]);
  } else if (idx < 32768 + 65536 + 16384) {  // W3: 256x64
    int j = idx - 98304;
    int k = j >> 6, c = j & 63;
    w3t[(size_t)c * 256 + k] = f2h(W3[j]);
  }
}

// ---------------------------------------------------------------------------
// CSR build
// ---------------------------------------------------------------------------
__global__ void deg_kernel(const int* __restrict__ dst, int* __restrict__ deg, int E) {
  int e = blockIdx.x * blockDim.x + threadIdx.x;
  if (e < E) atomicAdd(&deg[dst[e]], 1);
}

__global__ __launch_bounds__(256) void scan_partial(const int* __restrict__ deg,
                                                    int* __restrict__ rowptr,
                                                    int* __restrict__ blocksum, int n) {
  __shared__ int sdata[256];
  int t = threadIdx.x;
  int base = blockIdx.x * 1024 + t * 4;
  int v[4], s = 0;
  #pragma unroll
  for (int i = 0; i < 4; ++i) {
    v[i] = (base + i < n) ? deg[base + i] : 0;
    s += v[i];
  }
  sdata[t] = s;
  __syncthreads();
  for (int off = 1; off < 256; off <<= 1) {
    int x = (t >= off) ? sdata[t - off] : 0;
    __syncthreads();
    sdata[t] += x;
    __syncthreads();
  }
  int run = sdata[t] - s;
  #pragma unroll
  for (int i = 0; i < 4; ++i) {
    if (base + i < n) rowptr[base + i] = run;
    run += v[i];
  }
  if (t == 255) blocksum[blockIdx.x] = sdata[255];
}

__global__ __launch_bounds__(256) void scan_blocksums(int* __restrict__ blocksum, int nb) {
  __shared__ int sdata[256];
  int t = threadIdx.x;
  int v = (t < nb) ? blocksum[t] : 0;
  sdata[t] = v;
  __syncthreads();
  for (int off = 1; off < 256; off <<= 1) {
    int x = (t >= off) ? sdata[t - off] : 0;
    __syncthreads();
    sdata[t] += x;
    __syncthreads();
  }
  if (t < nb) blocksum[t] = sdata[t] - v;
}

__global__ void scan_add(int* __restrict__ rowptr, const int* __restrict__ blocksum,
                         int* __restrict__ cursor, int n, int E) {
  int idx = blockIdx.x * blockDim.x + threadIdx.x;
  if (idx < n) {
    rowptr[idx] += blocksum[idx >> 10];
    cursor[idx] = 0;
  }
  if (idx == n) rowptr[n] = E;
}

__global__ void scatter_kernel(const int* __restrict__ src, const int* __restrict__ dst,
                               const int* __restrict__ rowptr, int* __restrict__ cursor,
                               int* __restrict__ col_src, int E) {
  int e = blockIdx.x * blockDim.x + threadIdx.x;
  if (e >= E) return;
  int d = dst[e];
  int pos = rowptr[d] + atomicAdd(&cursor[d], 1);
  col_src[pos] = src[e];
}

// ---------------------------------------------------------------------------
// Fused per-dst softmax + aggregate, 1 dst/wave, HALF-WAVE layout:
// lanes 0-31 own 8 ch each (uint4 16B gathers) for even edges, lanes 32-63
// the same channels for odd edges; shfl_xor(32) merges. 2-pair unroll.
// fp16 h gather, fp16 feat out with bias+ELU. as_/ad_ LOG2E-scaled.
// ---------------------------------------------------------------------------
__global__ __launch_bounds__(256) void aggr_h(
    const int* __restrict__ rowptr, const int* __restrict__ col_src,
    const ushort* __restrict__ h, const float* __restrict__ as_,
    const float* __restrict__ ad_, const float* __restrict__ bias,
    ushort* __restrict__ of, int n) {
  int d = blockIdx.x * 4 + (threadIdx.x >> 6);
  if (d >= n) return;
  int lane = threadIdx.x & 63;
  int half = lane >> 5;
  int l = lane & 31;
  int c0 = l * 8;
  int hd = l >> 2;  // c0 / 32
  float ad_d = ad_[d * 8 + hd];
  float a0 = 0.f, a1 = 0.f, a2 = 0.f, a3 = 0.f;
  float a4 = 0.f, a5 = 0.f, a6 = 0.f, a7 = 0.f, denom = 0.f;
  const ushort* hp = h + c0;
  int beg = rowptr[d], end = rowptr[d + 1];
  int i = beg + half;
#if USE_DOT2
  // 2-pair unroll: per wave-iteration each half handles edges (i, i+2, i+4, i+6)
  for (; i + 6 < end; i += 8) {
    int s0 = col_src[i],     s1 = col_src[i + 2];
    int s2 = col_src[i + 4], s3 = col_src[i + 6];
    float l0 = as_[s0 * 8 + hd] + ad_d;
    float l1 = as_[s1 * 8 + hd] + ad_d;
    float l2 = as_[s2 * 8 + hd] + ad_d;
    float l3 = as_[s3 * 8 + hd] + ad_d;
    uint4 v0 = *(const uint4*)(hp + (size_t)s0 * 256);
    uint4 v1 = *(const uint4*)(hp + (size_t)s1 * 256);
    uint4 v2 = *(const uint4*)(hp + (size_t)s2 * 256);
    uint4 v3 = *(const uint4*)(hp + (size_t)s3 * 256);
    float e0 = fexp2(fmaxf(l0, 0.2f * l0));
    float e1 = fexp2(fmaxf(l1, 0.2f * l1));
    float e2 = fexp2(fmaxf(l2, 0.2f * l2));
    float e3 = fexp2(fmaxf(l3, 0.2f * l3));
    denom += (e0 + e1) + (e2 + e3);
    half2v ep01 = pack2(e0, e1);
    half2v ep23 = pack2(e2, e3);
    uint32_t p;
    p = __builtin_amdgcn_perm(v1.x, v0.x, 0x05040100u);
    a0 = __builtin_amdgcn_fdot2(ep01, __builtin_bit_cast(half2v, p), a0, false);
    p = __builtin_amdgcn_perm(v1.x, v0.x, 0x07060302u);
    a1 = __builtin_amdgcn_fdot2(ep01, __builtin_bit_cast(half2v, p), a1, false);
    p = __builtin_amdgcn_perm(v1.y, v0.y, 0x05040100u);
    a2 = __builtin_amdgcn_fdot2(ep01, __builtin_bit_cast(half2v, p), a2, false);
    p = __builtin_amdgcn_perm(v1.y, v0.y, 0x07060302u);
    a3 = __builtin_amdgcn_fdot2(ep01, __builtin_bit_cast(half2v, p), a3, false);
    p = __builtin_amdgcn_perm(v1.z, v0.z, 0x05040100u);
    a4 = __builtin_amdgcn_fdot2(ep01, __builtin_bit_cast(half2v, p), a4, false);
    p = __builtin_amdgcn_perm(v1.z, v0.z, 0x07060302u);
    a5 = __builtin_amdgcn_fdot2(ep01, __builtin_bit_cast(half2v, p), a5, false);
    p = __builtin_amdgcn_perm(v1.w, v0.w, 0x05040100u);
    a6 = __builtin_amdgcn_fdot2(ep01, __builtin_bit_cast(half2v, p), a6, false);
    p = __builtin_amdgcn_perm(v1.w, v0.w, 0x07060302u);
    a7 = __builtin_amdgcn_fdot2(ep01, __builtin_bit_cast(half2v, p), a7, false);
    p = __builtin_amdgcn_perm(v3.x, v2.x, 0x05040100u);
    a0 = __builtin_amdgcn_fdot2(ep23, __builtin_bit_cast(half2v, p), a0, false);
    p = __builtin_amdgcn_perm(v3.x, v2.x, 0x07060302u);
    a1 = __builtin_amdgcn_fdot2(ep23, __builtin_bit_cast(half2v, p), a1, false);
    p = __builtin_amdgcn_perm(v3.y, v2.y, 0x05040100u);
    a2 = __builtin_amdgcn_fdot2(ep23, __builtin_bit_cast(half2v, p), a2, false);
    p = __builtin_amdgcn_perm(v3.y, v2.y, 0x07060302u);
    a3 = __builtin_amdgcn_fdot2(ep23, __builtin_bit_cast(half2v, p), a3, false);
    p = __builtin_amdgcn_perm(v3.z, v2.z, 0x05040100u);
    a4 = __builtin_amdgcn_fdot2(ep23, __builtin_bit_cast(half2v, p), a4, false);
    p = __builtin_amdgcn_perm(v3.z, v2.z, 0x07060302u);
    a5 = __builtin_amdgcn_fdot2(ep23, __builtin_bit_cast(half2v, p), a5, false);
    p = __builtin_amdgcn_perm(v3.w, v2.w, 0x05040100u);
    a6 = __builtin_amdgcn_fdot2(ep23, __builtin_bit_cast(half2v, p), a6, false);
    p = __builtin_amdgcn_perm(v3.w, v2.w, 0x07060302u);
    a7 = __builtin_amdgcn_fdot2(ep23, __builtin_bit_cast(half2v, p), a7, false);
  }
  for (; i + 2 < end; i += 4) {  // single pair
    int s0 = col_src[i], s1 = col_src[i + 2];
    float l0 = as_[s0 * 8 + hd] + ad_d;
    float l1 = as_[s1 * 8 + hd] + ad_d;
    uint4 v0 = *(const uint4*)(hp + (size_t)s0 * 256);
    uint4 v1 = *(const uint4*)(hp + (size_t)s1 * 256);
    float e0 = fexp2(fmaxf(l0, 0.2f * l0));
    float e1 = fexp2(fmaxf(l1, 0.2f * l1));
    denom += e0 + e1;
    half2v ep = pack2(e0, e1);
    uint32_t p;
    p = __builtin_amdgcn_perm(v1.x, v0.x, 0x05040100u);
    a0 = __builtin_amdgcn_fdot2(ep, __builtin_bit_cast(half2v, p), a0, false);
    p = __builtin_amdgcn_perm(v1.x, v0.x, 0x07060302u);
    a1 = __builtin_amdgcn_fdot2(ep, __builtin_bit_cast(half2v, p), a1, false);
    p = __builtin_amdgcn_perm(v1.y, v0.y, 0x05040100u);
    a2 = __builtin_amdgcn_fdot2(ep, __builtin_bit_cast(half2v, p), a2, false);
    p = __builtin_amdgcn_perm(v1.y, v0.y, 0x07060302u);
    a3 = __builtin_amdgcn_fdot2(ep, __builtin_bit_cast(half2v, p), a3, false);
    p = __builtin_amdgcn_perm(v1.z, v0.z, 0x05040100u);
    a4 = __builtin_amdgcn_fdot2(ep, __builtin_bit_cast(half2v, p), a4, false);
    p = __builtin_amdgcn_perm(v1.z, v0.z, 0x07060302u);
    a5 = __builtin_amdgcn_fdot2(ep, __builtin_bit_cast(half2v, p), a5, false);
    p = __builtin_amdgcn_perm(v1.w, v0.w, 0x05040100u);
    a6 = __builtin_amdgcn_fdot2(ep, __builtin_bit_cast(half2v, p), a6, false);
    p = __builtin_amdgcn_perm(v1.w, v0.w, 0x07060302u);
    a7 = __builtin_amdgcn_fdot2(ep, __builtin_bit_cast(half2v, p), a7, false);
  }
#endif
  for (; i < end; i += 2) {  // singles (per-half tail)
    int s = col_src[i];
    float lg = as_[s * 8 + hd] + ad_d;
    float ev = fexp2(fmaxf(lg, 0.2f * lg));
    denom += ev;
    uint4 v = *(const uint4*)(hp + (size_t)s * 256);
    float2 p0 = h2x2(v.x), p1 = h2x2(v.y), p2 = h2x2(v.z), p3 = h2x2(v.w);
    a0 += ev * p0.x; a1 += ev * p0.y;
    a2 += ev * p1.x; a3 += ev * p1.y;
    a4 += ev * p2.x; a5 += ev * p2.y;
    a6 += ev * p3.x; a7 += ev * p3.y;
  }
  // merge the two halves (even-edge partials + odd-edge partials)
  a0 += __shfl_xor(a0, 32); a1 += __shfl_xor(a1, 32);
  a2 += __shfl_xor(a2, 32); a3 += __shfl_xor(a3, 32);
  a4 += __shfl_xor(a4, 32); a5 += __shfl_xor(a5, 32);
  a6 += __shfl_xor(a6, 32); a7 += __shfl_xor(a7, 32);
  denom += __shfl_xor(denom, 32);
  if (half == 0) {
    float inv = 1.f / (denom + 1e-16f);
    float4 b0 = *(const float4*)(bias + c0);
    float4 b1 = *(const float4*)(bias + c0 + 4);
    float vv[8];
    vv[0] = a0 * inv + b0.x; vv[1] = a1 * inv + b0.y;
    vv[2] = a2 * inv + b0.z; vv[3] = a3 * inv + b0.w;
    vv[4] = a4 * inv + b1.x; vv[5] = a5 * inv + b1.y;
    vv[6] = a6 * inv + b1.z; vv[7] = a7 * inv + b1.w;
    ushort8v hh;
    #pragma unroll
    for (int j = 0; j < 8; ++j) {
      float v = vv[j];
      v = (v > 0.f) ? v : expm1f(v);
      hh[j] = f2h(v);
    }
    *(ushort8v*)(of + (size_t)d * 256 + c0) = hh;
  }
}

// Layer 3: fp16 h gather, 4 dst/wave (16 lanes x 4ch), fdot2 MAC, fp32 out.
__global__ __launch_bounds__(256) void aggr_f3(
    const int* __restrict__ rowptr, const int* __restrict__ col_src,
    const ushort* __restrict__ h, const float* __restrict__ as_,
    const float* __restrict__ ad_, const float* __restrict__ bias,
    float* __restrict__ outp, int n) {
  int wid = (blockIdx.x * 256 + threadIdx.x) >> 6;
  int d = wid * 4 + ((threadIdx.x >> 4) & 3);
  if (d >= n) return;
  int l = threadIdx.x & 15;
  int c0 = l * 4;
  float ad_d = ad_[d];
  float a0 = 0.f, a1 = 0.f, a2 = 0.f, a3 = 0.f, denom = 0.f;
  const ushort* hp = h + c0;
  int beg = rowptr[d], end = rowptr[d + 1];
  int i = beg;
#if USE_DOT2
  const half2v onepk = {(_Float16)1.f, (_Float16)1.f};
  for (; i + 2 <= end; i += 2) {
    int s0 = col_src[i], s1 = col_src[i + 1];
    float l0 = as_[s0] + ad_d;
    float l1 = as_[s1] + ad_d;
    uint2 v0 = *(const uint2*)(hp + (size_t)s0 * 64);
    uint2 v1 = *(const uint2*)(hp + (size_t)s1 * 64);
    float e0 = fexp2(fmaxf(l0, 0.2f * l0));
    float e1 = fexp2(fmaxf(l1, 0.2f * l1));
    half2v ep = pack2(e0, e1);
    denom = __builtin_amdgcn_fdot2(ep, onepk, denom, false);
    uint32_t p;
    p = __builtin_amdgcn_perm(v1.x, v0.x, 0x05040100u);
    a0 = __builtin_amdgcn_fdot2(ep, __builtin_bit_cast(half2v, p), a0, false);
    p = __builtin_amdgcn_perm(v1.x, v0.x, 0x07060302u);
    a1 = __builtin_amdgcn_fdot2(ep, __builtin_bit_cast(half2v, p), a1, false);
    p = __builtin_amdgcn_perm(v1.y, v0.y, 0x05040100u);
    a2 = __builtin_amdgcn_fdot2(ep, __builtin_bit_cast(half2v, p), a2, false);
    p = __builtin_amdgcn_perm(v1.y, v0.y, 0x07060302u);
    a3 = __builtin_amdgcn_fdot2(ep, __builtin_bit_cast(half2v, p), a3, false);
  }
#endif
  for (; i < end; ++i) {
    int s = col_src[i];
    float lg = as_[s] + ad_d;
    float ev = fexp2(fmaxf(lg, 0.2f * lg));
    denom += ev;
    uint2 v = *(const uint2*)(hp + (size_t)s * 64);
    float2 p0 = h2x2(v.x), p1 = h2x2(v.y);
    a0 += ev * p0.x;
    a1 += ev * p0.y;
    a2 += ev * p1.x;
    a3 += ev * p1.y;
  }
  float inv = 1.f / (denom + 1e-16f);
  float4 r;
  r.x = a0 * inv + bias[c0 + 0];
  r.y = a1 * inv + bias[c0 + 1];
  r.z = a2 * inv + bias[c0 + 2];
  r.w = a3 * inv + bias[c0 + 3];
  *(float4*)(outp + (size_t)d * 64 + c0) = r;
}

// ---------------------------------------------------------------------------

extern "C" void kernel_launch(void* const* d_in, const int* in_sizes, int n_in,
                              void* d_out, int out_size, void* d_ws, size_t ws_size,
                              hipStream_t stream) {
  const float* x   = (const float*)d_in[0];
  const int*   ei  = (const int*)d_in[1];
  const float* W1  = (const float*)d_in[2];
  const float* aS1 = (const float*)d_in[3];
  const float* aD1 = (const float*)d_in[4];
  const float* b1  = (const float*)d_in[5];
  const float* W2  = (const float*)d_in[6];
  const float* aS2 = (const float*)d_in[7];
  const float* aD2 = (const float*)d_in[8];
  const float* b2  = (const float*)d_in[9];
  const float* W3  = (const float*)d_in[10];
  const float* aS3 = (const float*)d_in[11];
  const float* aD3 = (const float*)d_in[12];
  const float* b3  = (const float*)d_in[13];

  const int* srcp = ei;
  const int* dstp = ei + NEDGES;

  // ---- arena (~72 MB) ----
  char* base = (char*)d_ws;
  size_t o = 0;
  ushort* hbf  = (ushort*)(base + o); o += 25600000;
  ushort* ff   = (ushort*)(base + o); o += 25600000;
  ushort* f1   = (ushort*)(base + o); o += 12800000;
  float*  as_  = (float*)(base + o);  o += 1600000;
  float*  ad_  = (float*)(base + o);  o += 1600000;
  ushort* w1t  = (ushort*)(base + o); o += 65536;
  ushort* w2t  = (ushort*)(base + o); o += 131072;
  ushort* w3t  = (ushort*)(base + o); o += 32768;
  int* rowptr  = (int*)(base + o);    o += 200016;
  int* cursor  = (int*)(base + o);    o += 200000;
  int* colsrc  = (int*)(base + o);    o += 3200000;
  int* bsum    = (int*)(base + o);    o += 1024;
  float* outp  = (float*)d_out;

  // ---- CSR build ----
  hipMemsetAsync(cursor, 0, NNODES * sizeof(int), stream);
  deg_kernel<<<(NEDGES + 255) / 256, 256, 0, stream>>>(dstp, cursor, NEDGES);
  int nb = (NNODES + 1023) / 1024;  // 49
  scan_partial<<<nb, 256, 0, stream>>>(cursor, rowptr, bsum, NNODES);
  scan_blocksums<<<1, 256, 0, stream>>>(bsum, nb);
  scan_add<<<(NNODES + 256) / 256, 256, 0, stream>>>(rowptr, bsum, cursor, NNODES, NEDGES);
  scatter_kernel<<<(NEDGES + 255) / 256, 256, 0, stream>>>(srcp, dstp, rowptr, cursor,
                                                           colsrc, NEDGES);

  // ---- conversions ----
  cvt_h<<<(NNODES * 128 / 4 + 255) / 256, 256, 0, stream>>>(x, f1, NNODES * 128 / 4);
  cvt_w_all<<<(114688 + 255) / 256, 256, 0, stream>>>(W1, W2, W3, w1t, w2t, w3t);

  const int ga  = (NNODES + 3) / 4;
  const int ga4 = (NNODES + 15) / 16;
  const int gw  = (NNODES + 63) / 64;
  // ---- layer 1 ----
  gemm_wide<<<gw, 256, 0, stream>>>(f1, w1t, aS1, aD1, as_, ad_, hbf, NNODES, 128);
  aggr_h<<<ga, 256, 0, stream>>>(rowptr, colsrc, hbf, as_, ad_, b1, ff, NNODES);
  // ---- layer 2 ----
  gemm_wide<<<gw, 256, 0, stream>>>(ff, w2t, aS2, aD2, as_, ad_, hbf, NNODES, 256);
  aggr_h<<<ga, 256, 0, stream>>>(rowptr, colsrc, hbf, as_, ad_, b2, ff, NNODES);
  // ---- layer 3 ----
  gemm_mfma3<<<dim3(1, (NNODES + 127) / 128), 256, 0, stream>>>(
      ff, w3t, aS3, aD3, as_, ad_, hbf, NNODES, 256, 64);
  aggr_f3<<<ga4, 256, 0, stream>>>(rowptr, colsrc, hbf, as_, ad_, b3, outp, NNODES);
}

// Round 12
// 314.456 us; speedup vs baseline: 1.6795x; 1.0307x over previous
//
#include <hip/hip_runtime.h>
#include <hip/hip_bf16.h>
#include <hip/hip_fp16.h>
#include <stdint.h>

#define NNODES 50000
#define NEDGES 800000
#define LOG2E 1.44269504088896340736f

typedef float f32x4 __attribute__((ext_vector_type(4)));
typedef _Float16 half8 __attribute__((ext_vector_type(8)));
typedef _Float16 half2v __attribute__((ext_vector_type(2)));
typedef unsigned short ushort8v __attribute__((ext_vector_type(8)));

__device__ __forceinline__ ushort f2h(float f) {
  return __half_as_ushort(__float2half(f));  // RNE
}
__device__ __forceinline__ float2 h2x2(uint32_t u) {
  return __half22float2(__builtin_bit_cast(__half2, u));
}

#if __has_builtin(__builtin_amdgcn_fdot2) && __has_builtin(__builtin_amdgcn_perm) && __has_builtin(__builtin_amdgcn_cvt_pkrtz)
#define USE_DOT2 1
#else
#define USE_DOT2 0
#endif

__device__ __forceinline__ half2v pack2(float a, float b) {
  return __builtin_bit_cast(half2v, __builtin_amdgcn_cvt_pkrtz(a, b));
}

__device__ __forceinline__ float fexp2(float x) {
#if __has_builtin(__builtin_amdgcn_exp2f)
  return __builtin_amdgcn_exp2f(x);
#else
  return exp2f(x);
#endif
}

__device__ __forceinline__ void gload_lds16(const void* g, void* l) {
  __builtin_amdgcn_global_load_lds(
      (const __attribute__((address_space(1))) uint32_t*)g,
      (__attribute__((address_space(3))) uint32_t*)l, 16, 0, 0);
}

// ---------------------------------------------------------------------------
// fp16 MFMA GEMM, layers 1/2: C[M,256] = A @ Wt^T, fused alpha epilogue.
// BM=64, BN=256 (A panel read once), BK=64. fp16 out. Node-major alpha,
// LOG2E pre-scaled. AF32=1: A is fp32 (layer-1 x), staged raw and converted
// at ds_read time via cvt_pkrtz (deletes the standalone cvt_h pass).
// ---------------------------------------------------------------------------
template <int AF32>
__global__ __launch_bounds__(256) void gemm_wide(
    const ushort* __restrict__ A, const float* __restrict__ Af,
    const ushort* __restrict__ B,
    const float* __restrict__ a_src, const float* __restrict__ a_dst,
    float* __restrict__ as_out, float* __restrict__ ad_out,
    ushort* __restrict__ Cout, int M, int K) {
  __shared__ ushort As[AF32 ? 8192 : 4096];  // 16 KB (fp32) / 8 KB (fp16)
  __shared__ ushort Bs[256 * 64];            // 32 KB

  const int t = threadIdx.x;
  const int w = t >> 6, ln = t & 63;
  const int row0 = blockIdx.x * 64;
  const int wr = (w >> 1) * 32, wc = (w & 1) * 128;

  f32x4 acc[2][8] = {};

  const int nkt = K >> 6;
  for (int kt = 0; kt < nkt; ++kt) {
    const int k0 = kt << 6;
    if constexpr (AF32) {
      // stage A fp32: 64 rows x 64 floats = 16KB -> 4 loads/wave.
      // swizzle 16B slot: sg = sl ^ ((row&7)<<1)  (32B-chunk XOR at read).
      #pragma unroll
      for (int i = 0; i < 4; ++i) {
        int row4 = w * 4 + i;               // 16 packets of 4 rows
        int rloc = row4 * 4 + (ln >> 4);
        int sl = ln & 15;
        int sg = sl ^ ((rloc & 7) << 1);
        int grow = row0 + rloc; grow = grow < M ? grow : M - 1;
        gload_lds16(Af + (size_t)grow * K + k0 + sg * 4, As + row4 * 512);
      }
    } else {
      #pragma unroll
      for (int i = 0; i < 2; ++i) {
        int row8 = w * 2 + i;
        int rloc = row8 * 8 + (ln >> 3);
        int slot = (ln & 7) ^ (rloc & 7);
        int grow = row0 + rloc; grow = grow < M ? grow : M - 1;
        gload_lds16(A + (size_t)grow * K + k0 + slot * 8, As + row8 * 512);
      }
    }
    #pragma unroll
    for (int i = 0; i < 8; ++i) {
      int row8 = w * 8 + i;
      int rloc = row8 * 8 + (ln >> 3);
      int slot = (ln & 7) ^ (rloc & 7);
      gload_lds16(B + (size_t)rloc * K + k0 + slot * 8, Bs + row8 * 512);
    }
    __syncthreads();

    #pragma unroll
    for (int ks = 0; ks < 2; ++ks) {
      half8 a[2], b[8];
      #pragma unroll
      for (int i = 0; i < 2; ++i) {
        int row = wr + i * 16 + (ln & 15);
        if constexpr (AF32) {
          int ch = (ks * 4 + (ln >> 4)) ^ (row & 7);   // 32B chunk of 8 floats
          const float* rp = (const float*)As + row * 64 + ch * 8;
          f32x4 f0 = *(const f32x4*)rp;
          f32x4 f1 = *(const f32x4*)(rp + 4);
          union { half8 h; uint32_t u[4]; } cv;
          cv.u[0] = __builtin_bit_cast(uint32_t, pack2(f0[0], f0[1]));
          cv.u[1] = __builtin_bit_cast(uint32_t, pack2(f0[2], f0[3]));
          cv.u[2] = __builtin_bit_cast(uint32_t, pack2(f1[0], f1[1]));
          cv.u[3] = __builtin_bit_cast(uint32_t, pack2(f1[2], f1[3]));
          a[i] = cv.h;
        } else {
          int slot = (ks * 4 + (ln >> 4)) ^ (row & 7);
          a[i] = *(const half8*)(As + row * 64 + slot * 8);
        }
      }
      #pragma unroll
      for (int j = 0; j < 8; ++j) {
        int col = wc + j * 16 + (ln & 15);
        int slot = (ks * 4 + (ln >> 4)) ^ (col & 7);
        b[j] = *(const half8*)(Bs + col * 64 + slot * 8);
      }
      #pragma unroll
      for (int i = 0; i < 2; ++i)
        #pragma unroll
        for (int j = 0; j < 8; ++j)
          acc[i][j] = __builtin_amdgcn_mfma_f32_16x16x32_f16(a[i], b[j], acc[i][j], 0, 0, 0);
    }
    __syncthreads();
  }

  const int lx = ln & 15, g = ln >> 4;

  #pragma unroll
  for (int i = 0; i < 2; ++i)
    #pragma unroll
    for (int j = 0; j < 8; ++j)
      #pragma unroll
      for (int r = 0; r < 4; ++r) {
        int grow = row0 + wr + i * 16 + g * 4 + r;
        int gcol = wc + j * 16 + lx;
        if (grow < M) Cout[(size_t)grow * 256 + gcol] = f2h(acc[i][j][r]);
      }

  // ---- fused alpha epilogue (LOG2E pre-scaled, node-major) ----
  const int hbase = wc >> 5;
  float avs[8], avd[8];
  #pragma unroll
  for (int j = 0; j < 8; ++j) {
    avs[j] = a_src[wc + j * 16 + lx] * LOG2E;
    avd[j] = a_dst[wc + j * 16 + lx] * LOG2E;
  }
  #pragma unroll
  for (int i = 0; i < 2; ++i)
    #pragma unroll
    for (int r = 0; r < 4; ++r) {
      float ps[4] = {0.f, 0.f, 0.f, 0.f}, pd[4] = {0.f, 0.f, 0.f, 0.f};
      #pragma unroll
      for (int j = 0; j < 8; ++j) {
        float v = acc[i][j][r];
        ps[j >> 1] += v * avs[j];
        pd[j >> 1] += v * avd[j];
      }
      #pragma unroll
      for (int m = 1; m < 16; m <<= 1)
        #pragma unroll
        for (int q = 0; q < 4; ++q) {
          ps[q] += __shfl_xor(ps[q], m);
          pd[q] += __shfl_xor(pd[q], m);
        }
      if (lx == 0) {
        int grow = row0 + wr + i * 16 + g * 4 + r;
        if (grow < M) {
          #pragma unroll
          for (int q = 0; q < 4; ++q) {
            as_out[grow * 8 + hbase + q] = ps[q];
            ad_out[grow * 8 + hbase + q] = pd[q];
          }
        }
      }
    }
}

// ---------------------------------------------------------------------------
// fp16 MFMA GEMM, layer 3 (Ncols=64): BM=128, BN=64, BK=64. fp16 out.
// Fused alpha (H=1, C=64), LOG2E pre-scaled.
// ---------------------------------------------------------------------------
__global__ __launch_bounds__(256) void gemm_mfma3(
    const ushort* __restrict__ A, const ushort* __restrict__ B,
    const float* __restrict__ a_src, const float* __restrict__ a_dst,
    float* __restrict__ as_out, float* __restrict__ ad_out,
    ushort* __restrict__ Cout, int M, int K, int Ncols) {
  __shared__ ushort As[128 * 64];
  __shared__ ushort Bs[64 * 64];
  __shared__ float redS[2][128], redD[2][128];

  const int t = threadIdx.x;
  const int w = t >> 6, ln = t & 63;
  const int row0 = blockIdx.y * 128;
  const int col0 = blockIdx.x * 64;
  const int wr = (w >> 1) * 64, wc = (w & 1) * 32;

  f32x4 acc[4][2] = {};

  const int nkt = K >> 6;
  for (int kt = 0; kt < nkt; ++kt) {
    const int k0 = kt << 6;
    #pragma unroll
    for (int i = 0; i < 4; ++i) {
      int row8 = w * 4 + i;
      int rloc = row8 * 8 + (ln >> 3);
      int slot = (ln & 7) ^ (rloc & 7);
      int grow = row0 + rloc; grow = grow < M ? grow : M - 1;
      gload_lds16(A + (size_t)grow * K + k0 + slot * 8, As + row8 * 512);
    }
    #pragma unroll
    for (int i = 0; i < 2; ++i) {
      int row8 = w * 2 + i;
      int rloc = row8 * 8 + (ln >> 3);
      int slot = (ln & 7) ^ (rloc & 7);
      gload_lds16(B + (size_t)(col0 + rloc) * K + k0 + slot * 8, Bs + row8 * 512);
    }
    __syncthreads();

    #pragma unroll
    for (int ks = 0; ks < 2; ++ks) {
      half8 a[4], b[2];
      #pragma unroll
      for (int i = 0; i < 4; ++i) {
        int row = wr + i * 16 + (ln & 15);
        int slot = (ks * 4 + (ln >> 4)) ^ (row & 7);
        a[i] = *(const half8*)(As + row * 64 + slot * 8);
      }
      #pragma unroll
      for (int j = 0; j < 2; ++j) {
        int col = wc + j * 16 + (ln & 15);
        int slot = (ks * 4 + (ln >> 4)) ^ (col & 7);
        b[j] = *(const half8*)(Bs + col * 64 + slot * 8);
      }
      #pragma unroll
      for (int i = 0; i < 4; ++i)
        #pragma unroll
        for (int j = 0; j < 2; ++j)
          acc[i][j] = __builtin_amdgcn_mfma_f32_16x16x32_f16(a[i], b[j], acc[i][j], 0, 0, 0);
    }
    __syncthreads();
  }

  const int lx = ln & 15, g = ln >> 4;

  #pragma unroll
  for (int i = 0; i < 4; ++i)
    #pragma unroll
    for (int j = 0; j < 2; ++j)
      #pragma unroll
      for (int r = 0; r < 4; ++r) {
        int grow = row0 + wr + i * 16 + g * 4 + r;
        int gcol = col0 + wc + j * 16 + lx;
        if (grow < M) Cout[(size_t)grow * Ncols + gcol] = f2h(acc[i][j][r]);
      }

  float avs[2], avd[2];
  #pragma unroll
  for (int j = 0; j < 2; ++j) {
    avs[j] = a_src[wc + j * 16 + lx] * LOG2E;
    avd[j] = a_dst[wc + j * 16 + lx] * LOG2E;
  }
  #pragma unroll
  for (int i = 0; i < 4; ++i)
    #pragma unroll
    for (int r = 0; r < 4; ++r) {
      float ps = 0.f, pd = 0.f;
      #pragma unroll
      for (int j = 0; j < 2; ++j) {
        float v = acc[i][j][r];
        ps += v * avs[j];
        pd += v * avd[j];
      }
      #pragma unroll
      for (int m = 1; m < 16; m <<= 1) {
        ps += __shfl_xor(ps, m);
        pd += __shfl_xor(pd, m);
      }
      if (lx == 0) {
        int lrow = wr + i * 16 + g * 4 + r;
        redS[w & 1][lrow] = ps;
        redD[w & 1][lrow] = pd;
      }
    }
  __syncthreads();
  if (t < 128) {
    int grow = row0 + t;
    if (grow < M) {
      as_out[grow] = redS[0][t] + redS[1][t];
      ad_out[grow] = redD[0][t] + redD[1][t];
    }
  }
}

// ---------------------------------------------------------------------------
// prep: in-degree count (atomics) + all three weight transposes, one launch.
// ---------------------------------------------------------------------------
__global__ void prep_kernel(const int* __restrict__ dst, int* __restrict__ deg,
                            const float* __restrict__ W1, const float* __restrict__ W2,
                            const float* __restrict__ W3, ushort* __restrict__ w1t,
                            ushort* __restrict__ w2t, ushort* __restrict__ w3t) {
  int idx = blockIdx.x * blockDim.x + threadIdx.x;
  if (idx < NEDGES) {
    atomicAdd(&deg[dst[idx]], 1);
    return;
  }
  int j = idx - NEDGES;
  if (j < 32768) {                         // W1: 128x256
    int k = j >> 8, c = j & 255;
    w1t[(size_t)c * 128 + k] = f2h(W1[j]);
  } else if (j < 32768 + 65536) {          // W2: 256x256
    int q = j - 32768;
    int k = q >> 8, c = q & 255;
    w2t[(size_t)c * 256 + k] = f2h(W2[q]);
  } else if (j < 32768 + 65536 + 16384) {  // W3: 256x64
    int q = j - 98304;
    int k = q >> 6, c = q & 63;
    w3t[(size_t)c * 256 + k] = f2h(W3[q]);
  }
}

// ---------------------------------------------------------------------------
// CSR build
// ---------------------------------------------------------------------------
__global__ __launch_bounds__(256) void scan_partial(const int* __restrict__ deg,
                                                    int* __restrict__ rowptr,
                                                    int* __restrict__ blocksum, int n) {
  __shared__ int sdata[256];
  int t = threadIdx.x;
  int base = blockIdx.x * 1024 + t * 4;
  int v[4], s = 0;
  #pragma unroll
  for (int i = 0; i < 4; ++i) {
    v[i] = (base + i < n) ? deg[base + i] : 0;
    s += v[i];
  }
  sdata[t] = s;
  __syncthreads();
  for (int off = 1; off < 256; off <<= 1) {
    int x = (t >= off) ? sdata[t - off] : 0;
    __syncthreads();
    sdata[t] += x;
    __syncthreads();
  }
  int run = sdata[t] - s;
  #pragma unroll
  for (int i = 0; i < 4; ++i) {
    if (base + i < n) rowptr[base + i] = run;
    run += v[i];
  }
  if (t == 255) blocksum[blockIdx.x] = sdata[255];
}

// block-sum scan folded in (each block rescans the <=64 partial sums locally);
// also re-zeroes cursor for the scatter pass.
__global__ void scan_add(int* __restrict__ rowptr, const int* __restrict__ blocksum,
                         int* __restrict__ cursor, int n, int E, int nb) {
  __shared__ int soff[64];
  int t = threadIdx.x;
  if (t == 0) {
    int run = 0;
    for (int i = 0; i < nb; ++i) { soff[i] = run; run += blocksum[i]; }
  }
  __syncthreads();
  int idx = blockIdx.x * blockDim.x + t;
  if (idx < n) {
    rowptr[idx] += soff[idx >> 10];
    cursor[idx] = 0;
  }
  if (idx == n) rowptr[n] = E;
}

__global__ void scatter_kernel(const int* __restrict__ src, const int* __restrict__ dst,
                               const int* __restrict__ rowptr, int* __restrict__ cursor,
                               int* __restrict__ col_src, int E) {
  int e = blockIdx.x * blockDim.x + threadIdx.x;
  if (e >= E) return;
  int d = dst[e];
  int pos = rowptr[d] + atomicAdd(&cursor[d], 1);
  col_src[pos] = src[e];
}

// ---------------------------------------------------------------------------
// Fused per-dst softmax + aggregate, 1 dst/wave, HALF-WAVE layout (r11).
// ---------------------------------------------------------------------------
__global__ __launch_bounds__(256) void aggr_h(
    const int* __restrict__ rowptr, const int* __restrict__ col_src,
    const ushort* __restrict__ h, const float* __restrict__ as_,
    const float* __restrict__ ad_, const float* __restrict__ bias,
    ushort* __restrict__ of, int n) {
  int d = blockIdx.x * 4 + (threadIdx.x >> 6);
  if (d >= n) return;
  int lane = threadIdx.x & 63;
  int half = lane >> 5;
  int l = lane & 31;
  int c0 = l * 8;
  int hd = l >> 2;  // c0 / 32
  float ad_d = ad_[d * 8 + hd];
  float a0 = 0.f, a1 = 0.f, a2 = 0.f, a3 = 0.f;
  float a4 = 0.f, a5 = 0.f, a6 = 0.f, a7 = 0.f, denom = 0.f;
  const ushort* hp = h + c0;
  int beg = rowptr[d], end = rowptr[d + 1];
  int i = beg + half;
#if USE_DOT2
  for (; i + 6 < end; i += 8) {
    int s0 = col_src[i],     s1 = col_src[i + 2];
    int s2 = col_src[i + 4], s3 = col_src[i + 6];
    float l0 = as_[s0 * 8 + hd] + ad_d;
    float l1 = as_[s1 * 8 + hd] + ad_d;
    float l2 = as_[s2 * 8 + hd] + ad_d;
    float l3 = as_[s3 * 8 + hd] + ad_d;
    uint4 v0 = *(const uint4*)(hp + (size_t)s0 * 256);
    uint4 v1 = *(const uint4*)(hp + (size_t)s1 * 256);
    uint4 v2 = *(const uint4*)(hp + (size_t)s2 * 256);
    uint4 v3 = *(const uint4*)(hp + (size_t)s3 * 256);
    float e0 = fexp2(fmaxf(l0, 0.2f * l0));
    float e1 = fexp2(fmaxf(l1, 0.2f * l1));
    float e2 = fexp2(fmaxf(l2, 0.2f * l2));
    float e3 = fexp2(fmaxf(l3, 0.2f * l3));
    denom += (e0 + e1) + (e2 + e3);
    half2v ep01 = pack2(e0, e1);
    half2v ep23 = pack2(e2, e3);
    uint32_t p;
    p = __builtin_amdgcn_perm(v1.x, v0.x, 0x05040100u);
    a0 = __builtin_amdgcn_fdot2(ep01, __builtin_bit_cast(half2v, p), a0, false);
    p = __builtin_amdgcn_perm(v1.x, v0.x, 0x07060302u);
    a1 = __builtin_amdgcn_fdot2(ep01, __builtin_bit_cast(half2v, p), a1, false);
    p = __builtin_amdgcn_perm(v1.y, v0.y, 0x05040100u);
    a2 = __builtin_amdgcn_fdot2(ep01, __builtin_bit_cast(half2v, p), a2, false);
    p = __builtin_amdgcn_perm(v1.y, v0.y, 0x07060302u);
    a3 = __builtin_amdgcn_fdot2(ep01, __builtin_bit_cast(half2v, p), a3, false);
    p = __builtin_amdgcn_perm(v1.z, v0.z, 0x05040100u);
    a4 = __builtin_amdgcn_fdot2(ep01, __builtin_bit_cast(half2v, p), a4, false);
    p = __builtin_amdgcn_perm(v1.z, v0.z, 0x07060302u);
    a5 = __builtin_amdgcn_fdot2(ep01, __builtin_bit_cast(half2v, p), a5, false);
    p = __builtin_amdgcn_perm(v1.w, v0.w, 0x05040100u);
    a6 = __builtin_amdgcn_fdot2(ep01, __builtin_bit_cast(half2v, p), a6, false);
    p = __builtin_amdgcn_perm(v1.w, v0.w, 0x07060302u);
    a7 = __builtin_amdgcn_fdot2(ep01, __builtin_bit_cast(half2v, p), a7, false);
    p = __builtin_amdgcn_perm(v3.x, v2.x, 0x05040100u);
    a0 = __builtin_amdgcn_fdot2(ep23, __builtin_bit_cast(half2v, p), a0, false);
    p = __builtin_amdgcn_perm(v3.x, v2.x, 0x07060302u);
    a1 = __builtin_amdgcn_fdot2(ep23, __builtin_bit_cast(half2v, p), a1, false);
    p = __builtin_amdgcn_perm(v3.y, v2.y, 0x05040100u);
    a2 = __builtin_amdgcn_fdot2(ep23, __builtin_bit_cast(half2v, p), a2, false);
    p = __builtin_amdgcn_perm(v3.y, v2.y, 0x07060302u);
    a3 = __builtin_amdgcn_fdot2(ep23, __builtin_bit_cast(half2v, p), a3, false);
    p = __builtin_amdgcn_perm(v3.z, v2.z, 0x05040100u);
    a4 = __builtin_amdgcn_fdot2(ep23, __builtin_bit_cast(half2v, p), a4, false);
    p = __builtin_amdgcn_perm(v3.z, v2.z, 0x07060302u);
    a5 = __builtin_amdgcn_fdot2(ep23, __builtin_bit_cast(half2v, p), a5, false);
    p = __builtin_amdgcn_perm(v3.w, v2.w, 0x05040100u);
    a6 = __builtin_amdgcn_fdot2(ep23, __builtin_bit_cast(half2v, p), a6, false);
    p = __builtin_amdgcn_perm(v3.w, v2.w, 0x07060302u);
    a7 = __builtin_amdgcn_fdot2(ep23, __builtin_bit_cast(half2v, p), a7, false);
  }
  for (; i + 2 < end; i += 4) {
    int s0 = col_src[i], s1 = col_src[i + 2];
    float l0 = as_[s0 * 8 + hd] + ad_d;
    float l1 = as_[s1 * 8 + hd] + ad_d;
    uint4 v0 = *(const uint4*)(hp + (size_t)s0 * 256);
    uint4 v1 = *(const uint4*)(hp + (size_t)s1 * 256);
    float e0 = fexp2(fmaxf(l0, 0.2f * l0));
    float e1 = fexp2(fmaxf(l1, 0.2f * l1));
    denom += e0 + e1;
    half2v ep = pack2(e0, e1);
    uint32_t p;
    p = __builtin_amdgcn_perm(v1.x, v0.x, 0x05040100u);
    a0 = __builtin_amdgcn_fdot2(ep, __builtin_bit_cast(half2v, p), a0, false);
    p = __builtin_amdgcn_perm(v1.x, v0.x, 0x07060302u);
    a1 = __builtin_amdgcn_fdot2(ep, __builtin_bit_cast(half2v, p), a1, false);
    p = __builtin_amdgcn_perm(v1.y, v0.y, 0x05040100u);
    a2 = __builtin_amdgcn_fdot2(ep, __builtin_bit_cast(half2v, p), a2, false);
    p = __builtin_amdgcn_perm(v1.y, v0.y, 0x07060302u);
    a3 = __builtin_amdgcn_fdot2(ep, __builtin_bit_cast(half2v, p), a3, false);
    p = __builtin_amdgcn_perm(v1.z, v0.z, 0x05040100u);
    a4 = __builtin_amdgcn_fdot2(ep, __builtin_bit_cast(half2v, p), a4, false);
    p = __builtin_amdgcn_perm(v1.z, v0.z, 0x07060302u);
    a5 = __builtin_amdgcn_fdot2(ep, __builtin_bit_cast(half2v, p), a5, false);
    p = __builtin_amdgcn_perm(v1.w, v0.w, 0x05040100u);
    a6 = __builtin_amdgcn_fdot2(ep, __builtin_bit_cast(half2v, p), a6, false);
    p = __builtin_amdgcn_perm(v1.w, v0.w, 0x07060302u);
    a7 = __builtin_amdgcn_fdot2(ep, __builtin_bit_cast(half2v, p), a7, false);
  }
#endif
  for (; i < end; i += 2) {
    int s = col_src[i];
    float lg = as_[s * 8 + hd] + ad_d;
    float ev = fexp2(fmaxf(lg, 0.2f * lg));
    denom += ev;
    uint4 v = *(const uint4*)(hp + (size_t)s * 256);
    float2 p0 = h2x2(v.x), p1 = h2x2(v.y), p2 = h2x2(v.z), p3 = h2x2(v.w);
    a0 += ev * p0.x; a1 += ev * p0.y;
    a2 += ev * p1.x; a3 += ev * p1.y;
    a4 += ev * p2.x; a5 += ev * p2.y;
    a6 += ev * p3.x; a7 += ev * p3.y;
  }
  a0 += __shfl_xor(a0, 32); a1 += __shfl_xor(a1, 32);
  a2 += __shfl_xor(a2, 32); a3 += __shfl_xor(a3, 32);
  a4 += __shfl_xor(a4, 32); a5 += __shfl_xor(a5, 32);
  a6 += __shfl_xor(a6, 32); a7 += __shfl_xor(a7, 32);
  denom += __shfl_xor(denom, 32);
  if (half == 0) {
    float inv = 1.f / (denom + 1e-16f);
    float4 b0 = *(const float4*)(bias + c0);
    float4 b1 = *(const float4*)(bias + c0 + 4);
    float vv[8];
    vv[0] = a0 * inv + b0.x; vv[1] = a1 * inv + b0.y;
    vv[2] = a2 * inv + b0.z; vv[3] = a3 * inv + b0.w;
    vv[4] = a4 * inv + b1.x; vv[5] = a5 * inv + b1.y;
    vv[6] = a6 * inv + b1.z; vv[7] = a7 * inv + b1.w;
    ushort8v hh;
    #pragma unroll
    for (int j = 0; j < 8; ++j) {
      float v = vv[j];
      v = (v > 0.f) ? v : expm1f(v);
      hh[j] = f2h(v);
    }
    *(ushort8v*)(of + (size_t)d * 256 + c0) = hh;
  }
}

// ---------------------------------------------------------------------------
// Layer 3: 1 dst/wave, 8 edge-groups x 8 lanes x 8ch (uint4 16B gathers),
// cross-group shfl reduce. fp16 h gather, fp32 out, no ELU.
// ---------------------------------------------------------------------------
__global__ __launch_bounds__(256) void aggr_f3(
    const int* __restrict__ rowptr, const int* __restrict__ col_src,
    const ushort* __restrict__ h, const float* __restrict__ as_,
    const float* __restrict__ ad_, const float* __restrict__ bias,
    float* __restrict__ outp, int n) {
  int d = blockIdx.x * 4 + (threadIdx.x >> 6);
  if (d >= n) return;
  int lane = threadIdx.x & 63;
  int g = lane >> 3;   // edge group 0..7
  int l = lane & 7;    // 8 ch each
  int c0 = l * 8;
  float ad_d = ad_[d];
  float a0 = 0.f, a1 = 0.f, a2 = 0.f, a3 = 0.f;
  float a4 = 0.f, a5 = 0.f, a6 = 0.f, a7 = 0.f, denom = 0.f;
  const ushort* hp = h + c0;
  int beg = rowptr[d], end = rowptr[d + 1];
  for (int i = beg + g; i < end; i += 8) {
    int s = col_src[i];
    float lg = as_[s] + ad_d;
    float ev = fexp2(fmaxf(lg, 0.2f * lg));
    denom += ev;
    uint4 v = *(const uint4*)(hp + (size_t)s * 64);
    float2 p0 = h2x2(v.x), p1 = h2x2(v.y), p2 = h2x2(v.z), p3 = h2x2(v.w);
    a0 += ev * p0.x; a1 += ev * p0.y;
    a2 += ev * p1.x; a3 += ev * p1.y;
    a4 += ev * p2.x; a5 += ev * p2.y;
    a6 += ev * p3.x; a7 += ev * p3.y;
  }
  #pragma unroll
  for (int m = 8; m < 64; m <<= 1) {
    a0 += __shfl_xor(a0, m); a1 += __shfl_xor(a1, m);
    a2 += __shfl_xor(a2, m); a3 += __shfl_xor(a3, m);
    a4 += __shfl_xor(a4, m); a5 += __shfl_xor(a5, m);
    a6 += __shfl_xor(a6, m); a7 += __shfl_xor(a7, m);
    denom += __shfl_xor(denom, m);
  }
  if (g == 0) {
    float inv = 1.f / (denom + 1e-16f);
    float4 b0 = *(const float4*)(bias + c0);
    float4 b1 = *(const float4*)(bias + c0 + 4);
    float4 r0, r1;
    r0.x = a0 * inv + b0.x; r0.y = a1 * inv + b0.y;
    r0.z = a2 * inv + b0.z; r0.w = a3 * inv + b0.w;
    r1.x = a4 * inv + b1.x; r1.y = a5 * inv + b1.y;
    r1.z = a6 * inv + b1.z; r1.w = a7 * inv + b1.w;
    *(float4*)(outp + (size_t)d * 64 + c0) = r0;
    *(float4*)(outp + (size_t)d * 64 + c0 + 4) = r1;
  }
}

// ---------------------------------------------------------------------------

extern "C" void kernel_launch(void* const* d_in, const int* in_sizes, int n_in,
                              void* d_out, int out_size, void* d_ws, size_t ws_size,
                              hipStream_t stream) {
  const float* x   = (const float*)d_in[0];
  const int*   ei  = (const int*)d_in[1];
  const float* W1  = (const float*)d_in[2];
  const float* aS1 = (const float*)d_in[3];
  const float* aD1 = (const float*)d_in[4];
  const float* b1  = (const float*)d_in[5];
  const float* W2  = (const float*)d_in[6];
  const float* aS2 = (const float*)d_in[7];
  const float* aD2 = (const float*)d_in[8];
  const float* b2  = (const float*)d_in[9];
  const float* W3  = (const float*)d_in[10];
  const float* aS3 = (const float*)d_in[11];
  const float* aD3 = (const float*)d_in[12];
  const float* b3  = (const float*)d_in[13];

  const int* srcp = ei;
  const int* dstp = ei + NEDGES;

  // ---- arena (~60 MB) ----
  char* base = (char*)d_ws;
  size_t o = 0;
  ushort* hbf  = (ushort*)(base + o); o += 25600000;
  ushort* ff   = (ushort*)(base + o); o += 25600000;
  float*  as_  = (float*)(base + o);  o += 1600000;
  float*  ad_  = (float*)(base + o);  o += 1600000;
  ushort* w1t  = (ushort*)(base + o); o += 65536;
  ushort* w2t  = (ushort*)(base + o); o += 131072;
  ushort* w3t  = (ushort*)(base + o); o += 32768;
  int* rowptr  = (int*)(base + o);    o += 200016;
  int* cursor  = (int*)(base + o);    o += 200000;
  int* colsrc  = (int*)(base + o);    o += 3200000;
  int* bsum    = (int*)(base + o);    o += 1024;
  float* outp  = (float*)d_out;

  // ---- CSR build + weight conversions ----
  hipMemsetAsync(cursor, 0, NNODES * sizeof(int), stream);
  prep_kernel<<<(NEDGES + 114688 + 255) / 256, 256, 0, stream>>>(
      dstp, cursor, W1, W2, W3, w1t, w2t, w3t);
  int nb = (NNODES + 1023) / 1024;  // 49
  scan_partial<<<nb, 256, 0, stream>>>(cursor, rowptr, bsum, NNODES);
  scan_add<<<(NNODES + 256) / 256, 256, 0, stream>>>(rowptr, bsum, cursor, NNODES,
                                                     NEDGES, nb);
  scatter_kernel<<<(NEDGES + 255) / 256, 256, 0, stream>>>(srcp, dstp, rowptr, cursor,
                                                           colsrc, NEDGES);

  const int ga = (NNODES + 3) / 4;
  const int gw = (NNODES + 63) / 64;
  // ---- layer 1 (fp32 x read directly; cvt fused into staging) ----
  gemm_wide<1><<<gw, 256, 0, stream>>>(nullptr, x, w1t, aS1, aD1, as_, ad_,
                                       hbf, NNODES, 128);
  aggr_h<<<ga, 256, 0, stream>>>(rowptr, colsrc, hbf, as_, ad_, b1, ff, NNODES);
  // ---- layer 2 ----
  gemm_wide<0><<<gw, 256, 0, stream>>>(ff, nullptr, w2t, aS2, aD2, as_, ad_,
                                       hbf, NNODES, 256);
  aggr_h<<<ga, 256, 0, stream>>>(rowptr, colsrc, hbf, as_, ad_, b2, ff, NNODES);
  // ---- layer 3 ----
  gemm_mfma3<<<dim3(1, (NNODES + 127) / 128), 256, 0, stream>>>(
      ff, w3t, aS3, aD3, as_, ad_, hbf, NNODES, 256, 64);
  aggr_f3<<<ga, 256, 0, stream>>>(rowptr, colsrc, hbf, as_, ad_, b3, outp, NNODES);
}